// Round 10
// baseline (276.143 us; speedup 1.0000x reference)
//
#include <hip/hip_runtime.h>
#include <stdint.h>

// SimpleMarkovModel: 2-state Markov chain, 200000 emitters x 500 frames.
// Bit-exact JAX partitionable Threefry-2x32 (verified rounds 1-9, absmax 0).
//
// R10: arrangement experiment under the product law (chain-units fixed at
// N/64 = 3125 across the chip):
//  - 256 blocks x 256 threads = exactly 1 block/CU: ZERO CU imbalance
//    (rounds 7-9 had 3.05 blocks/CU -> 14 CUs carried a 4th block, ~25%
//    straggler tail).
//  - 3 chains per THREAD (n = 3t,3t+1,3t+2) -> per-wave ILP=3 to cover
//    dependent-VALU latency even at 1 wave/SIMD.
//  - Leftover 3392 emitters ride as a wave-uniform 4th chain on the first
//    53 waves.
//  - Lean folded cipher (R9), 4-frame key groups, batched nt stores.

#define ROTL32(x, d) __builtin_amdgcn_alignbit((x), (x), 32 - (d))

__device__ __forceinline__ void tf2x32(uint32_t k0, uint32_t k1,
                                       uint32_t x0, uint32_t x1,
                                       uint32_t& o0, uint32_t& o1) {
  const uint32_t k2 = k0 ^ k1 ^ 0x1BD11BDAu;
  x0 += k0; x1 += k1;
#define TF_R(d) { x0 += x1; x1 = ROTL32(x1, d) ^ x0; }
  TF_R(13) TF_R(15) TF_R(26) TF_R(6)
  x0 += k1; x1 += k2 + 1u;
  TF_R(17) TF_R(29) TF_R(16) TF_R(24)
  x0 += k2; x1 += k0 + 2u;
  TF_R(13) TF_R(15) TF_R(26) TF_R(6)
  x0 += k0; x1 += k1 + 3u;
  TF_R(17) TF_R(29) TF_R(16) TF_R(24)
  x0 += k1; x1 += k2 + 4u;
  TF_R(13) TF_R(15) TF_R(26) TF_R(6)
  x0 += k2; x1 += k0 + 5u;
#undef TF_R
  o0 = x0; o1 = x1;
}

// Subkey table, zero-padded to cap.
__global__ void subkeys_kernel(uint2* __restrict__ ks, int nf, int cap) {
  const int f = blockIdx.x * blockDim.x + threadIdx.x;
  if (f < nf) {
    uint32_t a, b;
    tf2x32(0u, 42u, 0u, (uint32_t)f, a, b);
    ks[f] = make_uint2(a, b);
  } else if (f < cap) {
    ks[f] = make_uint2(0u, 0u);
  }
}

// Lean cipher (R9): x1in = counter + k1; injections folded via add3.
__device__ __forceinline__ uint32_t cipher(uint32_t k0, uint32_t k1,
                                           uint32_t k2, uint32_t c1,
                                           uint32_t c2, uint32_t c3,
                                           uint32_t c4, uint32_t c5,
                                           uint32_t x1in) {
  uint32_t x0 = k0 + x1in;
  uint32_t x1 = ROTL32(x1in, 13) ^ x0;
  x0 += x1; x1 = ROTL32(x1, 15) ^ x0;
  x0 += x1; x1 = ROTL32(x1, 26) ^ x0;
  x0 += x1; x1 = ROTL32(x1,  6) ^ x0;
  x1 += c1; x0 = x0 + k1 + x1;
  x1 = ROTL32(x1, 17) ^ x0;
  x0 += x1; x1 = ROTL32(x1, 29) ^ x0;
  x0 += x1; x1 = ROTL32(x1, 16) ^ x0;
  x0 += x1; x1 = ROTL32(x1, 24) ^ x0;
  x1 += c2; x0 = x0 + k2 + x1;
  x1 = ROTL32(x1, 13) ^ x0;
  x0 += x1; x1 = ROTL32(x1, 15) ^ x0;
  x0 += x1; x1 = ROTL32(x1, 26) ^ x0;
  x0 += x1; x1 = ROTL32(x1,  6) ^ x0;
  x1 += c3; x0 = x0 + k0 + x1;
  x1 = ROTL32(x1, 17) ^ x0;
  x0 += x1; x1 = ROTL32(x1, 29) ^ x0;
  x0 += x1; x1 = ROTL32(x1, 16) ^ x0;
  x0 += x1; x1 = ROTL32(x1, 24) ^ x0;
  x1 += c4; x0 = x0 + k1 + x1;
  x1 = ROTL32(x1, 13) ^ x0;
  x0 += x1; x1 = ROTL32(x1, 15) ^ x0;
  x0 += x1; x1 = ROTL32(x1, 26) ^ x0;
  x0 += x1; x1 = ROTL32(x1,  6) ^ x0;
  return (x0 + k2) ^ (x1 + c5);
}

// NC interleaved chains over all frames. base[j] = 2*n_j; noff[j] = n_j.
template <int NC>
__device__ __forceinline__ void run_nc(
    const uint2* __restrict__ ks, float* __restrict__ out,
    const uint32_t* __restrict__ base, const int* __restrict__ noff,
    uint32_t* __restrict__ s, int N, int nf,
    uint32_t tsh0, uint32_t tsh1, uint32_t sw0, uint32_t sw1) {
  uint32_t thr[NC];
#pragma unroll
  for (int j = 0; j < NC; ++j) thr[j] = s[j] ? tsh1 : tsh0;

  const int ng = nf / 4;
  for (int g = 0; g < ng; ++g) {
    const int f0 = 4 * g;
    uint2 k[4];
#pragma unroll
    for (int i = 0; i < 4; ++i) k[i] = ks[f0 + i];   // uniform s_loads

    uint32_t vals[4][NC];
#pragma unroll
    for (int i = 0; i < 4; ++i) {
      const uint32_t k0 = k[i].x, k1 = k[i].y;
      const uint32_t k2 = k0 ^ k1 ^ 0x1BD11BDAu;     // SALU
      const uint32_t c1 = k2 + 1u, c2 = k0 + 2u, c3 = k1 + 3u,
                     c4 = k2 + 4u, c5 = k0 + 5u;
#pragma unroll
      for (int j = 0; j < NC; ++j) {                 // independent chains
        const uint32_t r = cipher(k0, k1, k2, c1, c2, c3, c4, c5,
                                  base[j] + s[j] + k1);
        s[j] ^= (r < thr[j]) ? sw1 : sw0;
        thr[j] = s[j] ? tsh1 : tsh0;
        vals[i][j] = s[j] ? 0u : 0x3f800000u;
      }
    }
#pragma unroll
    for (int i = 0; i < 4; ++i) {
      uint32_t* row = (uint32_t*)out + (size_t)(f0 + i) * N;
#pragma unroll
      for (int j = 0; j < NC; ++j)
        __builtin_nontemporal_store(vals[i][j], row + noff[j]);
    }
  }
  for (int f = ng * 4; f < nf; ++f) {                // tail frames
    const uint2 kk = ks[f];
    const uint32_t k0 = kk.x, k1 = kk.y;
    const uint32_t k2 = k0 ^ k1 ^ 0x1BD11BDAu;
    const uint32_t c1 = k2 + 1u, c2 = k0 + 2u, c3 = k1 + 3u,
                   c4 = k2 + 4u, c5 = k0 + 5u;
    uint32_t* row = (uint32_t*)out + (size_t)f * N;
#pragma unroll
    for (int j = 0; j < NC; ++j) {
      const uint32_t r = cipher(k0, k1, k2, c1, c2, c3, c4, c5,
                                base[j] + s[j] + k1);
      s[j] ^= (r < thr[j]) ? sw1 : sw0;
      thr[j] = s[j] ? tsh1 : tsh0;
      __builtin_nontemporal_store(s[j] ? 0u : 0x3f800000u, row + noff[j]);
    }
  }
}

__device__ __forceinline__ void get_params(
    const float* transition, const float* tmat,
    uint32_t& tsh0, uint32_t& tsh1, uint32_t& sw0, uint32_t& sw1) {
  // u < p  <=>  bits < (ceil(p*2^23) << 9); clamp guards p ~ 1.0.
  const uint64_t t0w = ((uint64_t)(uint32_t)ceilf(transition[1] * 8388608.0f)) << 9;
  const uint64_t t1w = ((uint64_t)(uint32_t)ceilf(transition[3] * 8388608.0f)) << 9;
  tsh0 = (t0w > 0xFFFFFFFFull) ? 0xFFFFFFFFu : (uint32_t)t0w;
  tsh1 = (t1w > 0xFFFFFFFFull) ? 0xFFFFFFFFu : (uint32_t)t1w;
  sw0 = (tmat[1] != 0.0f) ? 1u : 0u;
  sw1 = (tmat[5] != 0.0f) ? 1u : 0u;
}

// Primary kernel: T threads; thread t owns n = 3t,3t+1,3t+2 (+ 3T+t if
// t < extra). Launch with grid*block == T.
__global__ __launch_bounds__(256) void markov3_kernel(
    const float* __restrict__ initial, const float* __restrict__ transition,
    const float* __restrict__ tmat, const uint2* __restrict__ ks,
    float* __restrict__ out, int N, int nf, int T, int extra) {
  const int t = blockIdx.x * blockDim.x + threadIdx.x;

  uint32_t tsh0, tsh1, sw0, sw1;
  get_params(transition, tmat, tsh0, tsh1, sw0, sw1);

  const int n0 = 3 * t;
  uint32_t s[4];
  uint32_t base[4];
  int noff[4];
#pragma unroll
  for (int j = 0; j < 3; ++j) {
    const int n = n0 + j;
    s[j] = (initial[2 * n] != 0.0f) ? 0u : 1u;
    base[j] = 2u * (uint32_t)n;
    noff[j] = n;
  }
  if (t < extra) {                      // wave-uniform for extra % 64 == 0
    const int n3 = 3 * T + t;
    s[3] = (initial[2 * n3] != 0.0f) ? 0u : 1u;
    base[3] = 2u * (uint32_t)n3;
    noff[3] = n3;
    run_nc<4>(ks, out, base, noff, s, N, nf, tsh0, tsh1, sw0, sw1);
  } else {
    run_nc<3>(ks, out, base, noff, s, N, nf, tsh0, tsh1, sw0, sw1);
  }
}

// Generic fallback: 1 emitter per thread (R9 structure), any N.
__global__ __launch_bounds__(256) void markov_generic_kernel(
    const float* __restrict__ initial, const float* __restrict__ transition,
    const float* __restrict__ tmat, const uint2* __restrict__ ks,
    float* __restrict__ out, int N, int nf) {
  const int n = blockIdx.x * blockDim.x + threadIdx.x;
  if (n >= N) return;
  uint32_t tsh0, tsh1, sw0, sw1;
  get_params(transition, tmat, tsh0, tsh1, sw0, sw1);
  uint32_t s[1] = {(initial[2 * n] != 0.0f) ? 0u : 1u};
  uint32_t base[1] = {2u * (uint32_t)n};
  int noff[1] = {n};
  run_nc<1>(ks, out, base, noff, s, N, nf, tsh0, tsh1, sw0, sw1);
}

// LDS-staged subkeys fallback (if d_ws too small), generic mapping.
__global__ __launch_bounds__(256) void markov_lds_kernel(
    const float* __restrict__ initial, const float* __restrict__ transition,
    const float* __restrict__ tmat, float* __restrict__ out,
    int N, int nf, int cap) {
  extern __shared__ uint2 kf[];
  for (int f = threadIdx.x; f < cap; f += blockDim.x) {
    uint2 k = make_uint2(0u, 0u);
    if (f < nf) {
      uint32_t a, b;
      tf2x32(0u, 42u, 0u, (uint32_t)f, a, b);
      k = make_uint2(a, b);
    }
    kf[f] = k;
  }
  __syncthreads();
  const int n = blockIdx.x * blockDim.x + threadIdx.x;
  if (n >= N) return;
  uint32_t tsh0, tsh1, sw0, sw1;
  get_params(transition, tmat, tsh0, tsh1, sw0, sw1);
  uint32_t s[1] = {(initial[2 * n] != 0.0f) ? 0u : 1u};
  uint32_t base[1] = {2u * (uint32_t)n};
  int noff[1] = {n};
  run_nc<1>(kf, out, base, noff, s, N, nf, tsh0, tsh1, sw0, sw1);
}

extern "C" void kernel_launch(void* const* d_in, const int* in_sizes, int n_in,
                              void* d_out, int out_size, void* d_ws, size_t ws_size,
                              hipStream_t stream) {
  const float* initial    = (const float*)d_in[0];
  const float* transition = (const float*)d_in[1];
  const float* tmat       = (const float*)d_in[2];
  float* out = (float*)d_out;

  const int N  = in_sizes[0] / 2;               // 200000 emitters
  const int nf = (N > 0) ? (out_size / N) : 0;  // 500 frames
  if (N <= 0 || nf <= 0) return;

  const int cap = ((nf + 3) / 4 + 1) * 4;       // padded subkey count
  const size_t need = (size_t)cap * sizeof(uint2);

  if (ws_size < need) {                         // no workspace: LDS fallback
    const int block = 256;
    const int grid = (N + block - 1) / block;
    markov_lds_kernel<<<grid, block, need, stream>>>(initial, transition,
                                                     tmat, out, N, nf, cap);
    return;
  }

  uint2* ks = (uint2*)d_ws;
  subkeys_kernel<<<(cap + 255) / 256, 256, 0, stream>>>(ks, nf, cap);

  const int T = 65536;                          // 256 blocks x 256 threads
  if (N >= 3 * T && N < 4 * T) {
    const int extra = N - 3 * T;                // 3392 for N=200000
    markov3_kernel<<<T / 256, 256, 0, stream>>>(initial, transition, tmat,
                                                ks, out, N, nf, T, extra);
  } else {
    const int block = 256;
    const int grid = (N + block - 1) / block;
    markov_generic_kernel<<<grid, block, 0, stream>>>(initial, transition,
                                                      tmat, ks, out, N, nf);
  }
}

// Round 12
// 272.239 us; speedup vs baseline: 1.0143x; 1.0143x over previous
//
#include <hip/hip_runtime.h>
#include <stdint.h>

// SimpleMarkovModel: 2-state Markov chain, 200000 emitters x 500 frames.
// Bit-exact JAX partitionable Threefry-2x32 (verified rounds 1-10, absmax 0).
//
// R12 = R11 with the compile fix (__builtin_nontemporal_store needs a clang
// ext_vector_type, not HIP's uint4 struct). Write-contiguity test: per
// 16-frame group, stage the block's 256 emitters x 16 frames in LDS
// (frame-major, ping-pong, 1 barrier/group), then each wave stores full
// 1 KB contiguous rows (dwordx4 x 64 lanes). Compute = R9 lean cipher.

#define ROTL32(x, d) __builtin_amdgcn_alignbit((x), (x), 32 - (d))

typedef uint32_t v4u __attribute__((ext_vector_type(4)));

__device__ __forceinline__ void tf2x32(uint32_t k0, uint32_t k1,
                                       uint32_t x0, uint32_t x1,
                                       uint32_t& o0, uint32_t& o1) {
  const uint32_t k2 = k0 ^ k1 ^ 0x1BD11BDAu;
  x0 += k0; x1 += k1;
#define TF_R(d) { x0 += x1; x1 = ROTL32(x1, d) ^ x0; }
  TF_R(13) TF_R(15) TF_R(26) TF_R(6)
  x0 += k1; x1 += k2 + 1u;
  TF_R(17) TF_R(29) TF_R(16) TF_R(24)
  x0 += k2; x1 += k0 + 2u;
  TF_R(13) TF_R(15) TF_R(26) TF_R(6)
  x0 += k0; x1 += k1 + 3u;
  TF_R(17) TF_R(29) TF_R(16) TF_R(24)
  x0 += k1; x1 += k2 + 4u;
  TF_R(13) TF_R(15) TF_R(26) TF_R(6)
  x0 += k2; x1 += k0 + 5u;
#undef TF_R
  o0 = x0; o1 = x1;
}

// Subkey table, zero-padded to cap.
__global__ void subkeys_kernel(uint2* __restrict__ ks, int nf, int cap) {
  const int f = blockIdx.x * blockDim.x + threadIdx.x;
  if (f < nf) {
    uint32_t a, b;
    tf2x32(0u, 42u, 0u, (uint32_t)f, a, b);
    ks[f] = make_uint2(a, b);
  } else if (f < cap) {
    ks[f] = make_uint2(0u, 0u);
  }
}

// Lean cipher (R9): x1in = counter + k1; injections folded via add3.
__device__ __forceinline__ uint32_t cipher(uint32_t k0, uint32_t k1,
                                           uint32_t k2, uint32_t c1,
                                           uint32_t c2, uint32_t c3,
                                           uint32_t c4, uint32_t c5,
                                           uint32_t x1in) {
  uint32_t x0 = k0 + x1in;
  uint32_t x1 = ROTL32(x1in, 13) ^ x0;
  x0 += x1; x1 = ROTL32(x1, 15) ^ x0;
  x0 += x1; x1 = ROTL32(x1, 26) ^ x0;
  x0 += x1; x1 = ROTL32(x1,  6) ^ x0;
  x1 += c1; x0 = x0 + k1 + x1;
  x1 = ROTL32(x1, 17) ^ x0;
  x0 += x1; x1 = ROTL32(x1, 29) ^ x0;
  x0 += x1; x1 = ROTL32(x1, 16) ^ x0;
  x0 += x1; x1 = ROTL32(x1, 24) ^ x0;
  x1 += c2; x0 = x0 + k2 + x1;
  x1 = ROTL32(x1, 13) ^ x0;
  x0 += x1; x1 = ROTL32(x1, 15) ^ x0;
  x0 += x1; x1 = ROTL32(x1, 26) ^ x0;
  x0 += x1; x1 = ROTL32(x1,  6) ^ x0;
  x1 += c3; x0 = x0 + k0 + x1;
  x1 = ROTL32(x1, 17) ^ x0;
  x0 += x1; x1 = ROTL32(x1, 29) ^ x0;
  x0 += x1; x1 = ROTL32(x1, 16) ^ x0;
  x0 += x1; x1 = ROTL32(x1, 24) ^ x0;
  x1 += c4; x0 = x0 + k1 + x1;
  x1 = ROTL32(x1, 13) ^ x0;
  x0 += x1; x1 = ROTL32(x1, 15) ^ x0;
  x0 += x1; x1 = ROTL32(x1, 26) ^ x0;
  x0 += x1; x1 = ROTL32(x1,  6) ^ x0;
  return (x0 + k2) ^ (x1 + c5);
}

__device__ __forceinline__ void get_params(
    const float* transition, const float* tmat,
    uint32_t& tsh0, uint32_t& tsh1, uint32_t& sw0, uint32_t& sw1) {
  // u < p  <=>  bits < (ceil(p*2^23) << 9); clamp guards p ~ 1.0.
  const uint64_t t0w = ((uint64_t)(uint32_t)ceilf(transition[1] * 8388608.0f)) << 9;
  const uint64_t t1w = ((uint64_t)(uint32_t)ceilf(transition[3] * 8388608.0f)) << 9;
  tsh0 = (t0w > 0xFFFFFFFFull) ? 0xFFFFFFFFu : (uint32_t)t0w;
  tsh1 = (t1w > 0xFFFFFFFFull) ? 0xFFFFFFFFu : (uint32_t)t1w;
  sw0 = (tmat[1] != 0.0f) ? 1u : 0u;
  sw1 = (tmat[5] != 0.0f) ? 1u : 0u;
}

// Transposed-store kernel. Requires N % 4 == 0. Block = 256 threads, one
// emitter per thread; per 16-frame group: LDS stage (frame-major), one
// barrier, then wave w stores rows 4w..4w+3 as 1 KB dwordx4 bursts.
__global__ __launch_bounds__(256) void markov_t_kernel(
    const float* __restrict__ initial, const float* __restrict__ transition,
    const float* __restrict__ tmat, const uint2* __restrict__ ks,
    float* __restrict__ out, int N, int nf) {
  __shared__ uint32_t buf[2][16 * 256];   // ping-pong, 32 KB

  const int t = (int)threadIdx.x;
  const int n0b = (int)blockIdx.x * 256;  // first emitter of this block
  const int n = n0b + t;
  const int rem = N - n0b;
  const int valid = rem < 256 ? rem : 256;     // emitters in this block
  const bool active = (t < valid);

  uint32_t tsh0, tsh1, sw0, sw1;
  get_params(transition, tmat, tsh0, tsh1, sw0, sw1);

  uint32_t s = 0u, thr = tsh0, base = 0u;
  if (active) {
    s = (initial[2 * n] != 0.0f) ? 0u : 1u;
    thr = s ? tsh1 : tsh0;
    base = 2u * (uint32_t)n;
  }

  const int w = t >> 6, l = t & 63;
  const int e0 = 4 * l;                   // emitter quad offset in block

  const int ng = nf / 16;
  for (int g = 0; g < ng; ++g) {
    const int f0 = g * 16;
    uint32_t* b = buf[g & 1];
    if (active) {
#pragma unroll
      for (int i = 0; i < 16; ++i) {
        const uint2 kk = ks[f0 + i];      // uniform -> s_load
        const uint32_t k0 = kk.x, k1 = kk.y;
        const uint32_t k2 = k0 ^ k1 ^ 0x1BD11BDAu;           // SALU
        const uint32_t c1 = k2 + 1u, c2 = k0 + 2u, c3 = k1 + 3u,
                       c4 = k2 + 4u, c5 = k0 + 5u;
        const uint32_t r = cipher(k0, k1, k2, c1, c2, c3, c4, c5,
                                  base + s + k1);
        s ^= (r < thr) ? sw1 : sw0;
        thr = s ? tsh1 : tsh0;
        b[i * 256 + t] = s ? 0u : 0x3f800000u;  // stride-1: conflict-free
      }
    }
    __syncthreads();  // single barrier per group (ping-pong makes it safe)
    if (e0 < valid) {
#pragma unroll
      for (int c = 0; c < 4; ++c) {
        const int r = 4 * w + c;
        const v4u v = *(const v4u*)&b[r * 256 + e0];  // ds_read_b128
        __builtin_nontemporal_store(
            v, (v4u*)(out + (size_t)(f0 + r) * N + (n0b + e0)));
      }
    }
  }
  // tail frames (4 for nf=500): direct per-thread stores
  for (int f = ng * 16; f < nf; ++f) {
    if (active) {
      const uint2 kk = ks[f];
      const uint32_t k0 = kk.x, k1 = kk.y;
      const uint32_t k2 = k0 ^ k1 ^ 0x1BD11BDAu;
      const uint32_t c1 = k2 + 1u, c2 = k0 + 2u, c3 = k1 + 3u,
                     c4 = k2 + 4u, c5 = k0 + 5u;
      const uint32_t r = cipher(k0, k1, k2, c1, c2, c3, c4, c5,
                                base + s + k1);
      s ^= (r < thr) ? sw1 : sw0;
      thr = s ? tsh1 : tsh0;
      __builtin_nontemporal_store(s ? 0u : 0x3f800000u,
                                  (uint32_t*)(out + (size_t)f * N) + n);
    }
  }
}

// Generic fallback: 1 emitter/thread, direct dword stores (any N).
__global__ __launch_bounds__(256) void markov_generic_kernel(
    const float* __restrict__ initial, const float* __restrict__ transition,
    const float* __restrict__ tmat, const uint2* __restrict__ ks,
    float* __restrict__ out, int N, int nf) {
  const int n = blockIdx.x * blockDim.x + threadIdx.x;
  if (n >= N) return;
  uint32_t tsh0, tsh1, sw0, sw1;
  get_params(transition, tmat, tsh0, tsh1, sw0, sw1);
  uint32_t s = (initial[2 * n] != 0.0f) ? 0u : 1u;
  uint32_t thr = s ? tsh1 : tsh0;
  const uint32_t base = 2u * (uint32_t)n;
  for (int f = 0; f < nf; ++f) {
    const uint2 kk = ks[f];
    const uint32_t k0 = kk.x, k1 = kk.y;
    const uint32_t k2 = k0 ^ k1 ^ 0x1BD11BDAu;
    const uint32_t c1 = k2 + 1u, c2 = k0 + 2u, c3 = k1 + 3u,
                   c4 = k2 + 4u, c5 = k0 + 5u;
    const uint32_t r = cipher(k0, k1, k2, c1, c2, c3, c4, c5, base + s + k1);
    s ^= (r < thr) ? sw1 : sw0;
    thr = s ? tsh1 : tsh0;
    __builtin_nontemporal_store(s ? 0u : 0x3f800000u,
                                (uint32_t*)(out + (size_t)f * N) + n);
  }
}

// LDS-staged subkeys fallback (if d_ws too small), generic mapping.
__global__ __launch_bounds__(256) void markov_lds_kernel(
    const float* __restrict__ initial, const float* __restrict__ transition,
    const float* __restrict__ tmat, float* __restrict__ out,
    int N, int nf, int cap) {
  extern __shared__ uint2 kf[];
  for (int f = threadIdx.x; f < cap; f += blockDim.x) {
    uint2 k = make_uint2(0u, 0u);
    if (f < nf) {
      uint32_t a, b;
      tf2x32(0u, 42u, 0u, (uint32_t)f, a, b);
      k = make_uint2(a, b);
    }
    kf[f] = k;
  }
  __syncthreads();
  const int n = blockIdx.x * blockDim.x + threadIdx.x;
  if (n >= N) return;
  uint32_t tsh0, tsh1, sw0, sw1;
  get_params(transition, tmat, tsh0, tsh1, sw0, sw1);
  uint32_t s = (initial[2 * n] != 0.0f) ? 0u : 1u;
  uint32_t thr = s ? tsh1 : tsh0;
  const uint32_t base = 2u * (uint32_t)n;
  for (int f = 0; f < nf; ++f) {
    const uint2 kk = kf[f];
    const uint32_t k0 = kk.x, k1 = kk.y;
    const uint32_t k2 = k0 ^ k1 ^ 0x1BD11BDAu;
    const uint32_t c1 = k2 + 1u, c2 = k0 + 2u, c3 = k1 + 3u,
                   c4 = k2 + 4u, c5 = k0 + 5u;
    const uint32_t r = cipher(k0, k1, k2, c1, c2, c3, c4, c5, base + s + k1);
    s ^= (r < thr) ? sw1 : sw0;
    thr = s ? tsh1 : tsh0;
    __builtin_nontemporal_store(s ? 0u : 0x3f800000u,
                                (uint32_t*)(out + (size_t)f * N) + n);
  }
}

extern "C" void kernel_launch(void* const* d_in, const int* in_sizes, int n_in,
                              void* d_out, int out_size, void* d_ws, size_t ws_size,
                              hipStream_t stream) {
  const float* initial    = (const float*)d_in[0];
  const float* transition = (const float*)d_in[1];
  const float* tmat       = (const float*)d_in[2];
  float* out = (float*)d_out;

  const int N  = in_sizes[0] / 2;               // 200000 emitters
  const int nf = (N > 0) ? (out_size / N) : 0;  // 500 frames
  if (N <= 0 || nf <= 0) return;

  const int block = 256;
  const int grid = (N + block - 1) / block;     // 782 blocks

  const int cap = ((nf + 15) / 16 + 1) * 16;    // padded subkey count
  const size_t need = (size_t)cap * sizeof(uint2);

  if (ws_size < need) {                         // no workspace: LDS fallback
    markov_lds_kernel<<<grid, block, need, stream>>>(initial, transition,
                                                     tmat, out, N, nf, cap);
    return;
  }

  uint2* ks = (uint2*)d_ws;
  subkeys_kernel<<<(cap + 255) / 256, 256, 0, stream>>>(ks, nf, cap);

  if ((N % 4) == 0) {
    markov_t_kernel<<<grid, block, 0, stream>>>(initial, transition, tmat,
                                                ks, out, N, nf);
  } else {
    markov_generic_kernel<<<grid, block, 0, stream>>>(initial, transition,
                                                      tmat, ks, out, N, nf);
  }
}